// Round 4
// baseline (1424.441 us; speedup 1.0000x reference)
//
#include <hip/hip_runtime.h>

#define TSTEPS 1024

// 4 FMAs accumulating a float4 LDS broadcast against a register weight array.
#define ACC4(acc_, wt_, q_, hv_)                    \
    acc_ = fmaf((wt_)[4*(q_)+0], (hv_).x, acc_);    \
    acc_ = fmaf((wt_)[4*(q_)+1], (hv_).y, acc_);    \
    acc_ = fmaf((wt_)[4*(q_)+2], (hv_).z, acc_);    \
    acc_ = fmaf((wt_)[4*(q_)+3], (hv_).w, acc_);

__device__ __forceinline__ float fast_rcp(float x) { return __builtin_amdgcn_rcpf(x); }
__device__ __forceinline__ float fast_sigmoid(float x) {
    return fast_rcp(1.0f + __expf(-x));
}
__device__ __forceinline__ float fast_tanh(float x) {
    float e = __expf(2.0f * x);
    return 1.0f - 2.0f * fast_rcp(e + 1.0f);
}

// Three waves per block (one block per batch element):
//   wave0: GRU1 r,z gates. lane j owns W_hh1 rows {j, 64+j} (128 regs).
//          Writes sigmoid(r), sigmoid(z) to LDS before B1.
//   wave1: GRU1 n gate (row 128+j, 64 regs) + GRU2 h-part (W_hh2 rows
//          {u,32+u,64+u}, K-half per lane, 48 regs). Owns the h1 update
//          (reads r,z after B1, writes s_h1[t&1]).
//   wave2: GRU2 x-part (W_ih2 rows {u,32+u,64+u}, K-half, 96 regs) + h2
//          gate math + h2 update, one step behind (uses h1(t-1), h2(t-2)).
// Two barriers per tick. All weights fit in arch VGPRs (<=170 budget at
// 3 waves/SIMD) -- the point of this split is to eliminate the AGPR
// spill moves that dominated R3's VALU time.
__global__ __launch_bounds__(192, 3)
void gru2_encoder(const float* __restrict__ x,
                  const float* __restrict__ W_ih1,
                  const float* __restrict__ W_hh1,
                  const float* __restrict__ b_ih1,
                  const float* __restrict__ b_hh1,
                  const float* __restrict__ W_ih2,
                  const float* __restrict__ W_hh2,
                  const float* __restrict__ b_ih2,
                  const float* __restrict__ b_hh2,
                  float* __restrict__ out)
{
    const int b    = blockIdx.x;
    const int tid  = threadIdx.x;
    const int lane = tid & 63;
    const int wid  = tid >> 6;

    __shared__ __align__(16) float s_h1[2][64];  // h1 double buffer
    __shared__ __align__(16) float s_r[64];      // sigmoid(r1), wave0 -> wave1
    __shared__ __align__(16) float s_z[64];      // sigmoid(z1), wave0 -> wave1
    __shared__ __align__(16) float s_gh2[96];    // W_hh2 @ h2 partials, wave1 -> wave2
    __shared__ __align__(16) float s_h2[32];     // h2 broadcast, wave2 -> wave1

    // zero-init LDS (d_ws/out poisoning means we must not rely on prior state)
    if (tid < 64) { s_h1[0][tid] = 0.0f; s_h1[1][tid] = 0.0f; s_r[tid] = 0.0f; s_z[tid] = 0.0f; }
    else if (tid < 160) { s_gh2[tid - 64] = 0.0f; }
    else { s_h2[tid - 160] = 0.0f; }
    __syncthreads();

    const float* xrow = x + (size_t)b * TSTEPS;

    if (wid == 0) {
        // ================= WAVE 0 : GRU1 r,z =================
        const int j = lane;
        float wr[64], wz[64];
        {
            const float4* pr = (const float4*)(W_hh1 + (size_t)(j) * 64);
            const float4* pz = (const float4*)(W_hh1 + (size_t)(64 + j) * 64);
            #pragma unroll
            for (int q = 0; q < 16; ++q) {
                float4 v;
                v = pr[q]; wr[4*q]=v.x; wr[4*q+1]=v.y; wr[4*q+2]=v.z; wr[4*q+3]=v.w;
                v = pz[q]; wz[4*q]=v.x; wz[4*q+1]=v.y; wz[4*q+2]=v.z; wz[4*q+3]=v.w;
            }
        }
        const float wx_r = W_ih1[j];
        const float wx_z = W_ih1[64 + j];
        const float br = b_ih1[j]      + b_hh1[j];
        const float bz = b_ih1[64 + j] + b_hh1[64 + j];

        float xv = xrow[0];
        for (int t = 0; t <= TSTEPS; ++t) {
            if (t < TSTEPS) {
                float xv_next = (t + 1 < TSTEPS) ? xrow[t + 1] : 0.0f;
                const float4* ph = (const float4*)s_h1[(t + 1) & 1];  // h1(t-1)
                float ar = fmaf(wx_r, xv, br);
                float az = fmaf(wx_z, xv, bz);
                #pragma unroll
                for (int q = 0; q < 16; ++q) {
                    float4 hv = ph[q];
                    ACC4(ar, wr, q, hv)
                    ACC4(az, wz, q, hv)
                }
                s_r[j] = fast_sigmoid(ar);
                s_z[j] = fast_sigmoid(az);
                xv = xv_next;
            }
            __syncthreads();   // B1
            __syncthreads();   // B2
        }
    } else if (wid == 1) {
        // ======== WAVE 1 : GRU1 n gate + GRU2 h-part + h1 update ========
        const int j    = lane;
        const int u    = lane & 31;
        const int half = lane >> 5;
        float wn[64];
        {
            const float4* pn = (const float4*)(W_hh1 + (size_t)(128 + j) * 64);
            #pragma unroll
            for (int q = 0; q < 16; ++q) {
                float4 v = pn[q];
                wn[4*q]=v.x; wn[4*q+1]=v.y; wn[4*q+2]=v.z; wn[4*q+3]=v.w;
            }
        }
        float whr[16], whz[16], whn[16];   // W_hh2 rows u,32+u,64+u, cols [half*16,+16)
        {
            const float4* qr = (const float4*)(W_hh2 + (size_t)(u)      * 32 + half * 16);
            const float4* qz = (const float4*)(W_hh2 + (size_t)(32 + u) * 32 + half * 16);
            const float4* qn = (const float4*)(W_hh2 + (size_t)(64 + u) * 32 + half * 16);
            #pragma unroll
            for (int q = 0; q < 4; ++q) {
                float4 v;
                v = qr[q]; whr[4*q]=v.x; whr[4*q+1]=v.y; whr[4*q+2]=v.z; whr[4*q+3]=v.w;
                v = qz[q]; whz[4*q]=v.x; whz[4*q+1]=v.y; whz[4*q+2]=v.z; whz[4*q+3]=v.w;
                v = qn[q]; whn[4*q]=v.x; whn[4*q+1]=v.y; whn[4*q+2]=v.z; whn[4*q+3]=v.w;
            }
        }
        const float wx_n = W_ih1[128 + j];
        const float bnx  = b_ih1[128 + j];
        const float bnh  = b_hh1[128 + j];

        float h1 = 0.0f;
        float xv = xrow[0];
        for (int t = 0; t <= TSTEPS; ++t) {
            // GRU2 h-part over h2(t-2) (s_h2 still holds it pre-B1). Runs
            // unconditionally: at t=0 it writes zeros (s_h2==0), harmless.
            {
                const float4* p2 = (const float4*)(&s_h2[half * 16]);
                float aR = 0.0f, aZ = 0.0f, aN = 0.0f;
                #pragma unroll
                for (int q = 0; q < 4; ++q) {
                    float4 hv = p2[q];
                    ACC4(aR, whr, q, hv)
                    ACC4(aZ, whz, q, hv)
                    ACC4(aN, whn, q, hv)
                }
                aR += __shfl_xor(aR, 32);
                aZ += __shfl_xor(aZ, 32);
                aN += __shfl_xor(aN, 32);
                if (lane < 32) { s_gh2[u] = aR; s_gh2[32 + u] = aZ; s_gh2[64 + u] = aN; }
            }
            float nh = bnh, nx = 0.0f, xv_next = 0.0f;
            if (t < TSTEPS) {
                xv_next = (t + 1 < TSTEPS) ? xrow[t + 1] : 0.0f;
                nx = fmaf(wx_n, xv, bnx);
                const float4* ph = (const float4*)s_h1[(t + 1) & 1];  // h1(t-1)
                #pragma unroll
                for (int q = 0; q < 16; ++q) {
                    float4 hv = ph[q];
                    ACC4(nh, wn, q, hv)
                }
            }
            __syncthreads();   // B1: r,z and gh2 published
            if (t < TSTEPS) {
                float r = s_r[j];
                float z = s_z[j];
                float n = fast_tanh(nx + r * nh);
                h1 = n + z * (h1 - n);
                s_h1[t & 1][j] = h1;
                xv = xv_next;
            }
            __syncthreads();   // B2: h1(t) published
        }
    } else {
        // ======== WAVE 2 : GRU2 x-part + gate math + h2 update (1 step behind) ========
        const int u    = lane & 31;
        const int half = lane >> 5;
        float wir[32], wiz[32], win[32];   // W_ih2 rows u,32+u,64+u, cols [half*32,+32)
        {
            const float4* pr = (const float4*)(W_ih2 + (size_t)(u)      * 64 + half * 32);
            const float4* pz = (const float4*)(W_ih2 + (size_t)(32 + u) * 64 + half * 32);
            const float4* pn = (const float4*)(W_ih2 + (size_t)(64 + u) * 64 + half * 32);
            #pragma unroll
            for (int q = 0; q < 8; ++q) {
                float4 v;
                v = pr[q]; wir[4*q]=v.x; wir[4*q+1]=v.y; wir[4*q+2]=v.z; wir[4*q+3]=v.w;
                v = pz[q]; wiz[4*q]=v.x; wiz[4*q+1]=v.y; wiz[4*q+2]=v.z; wiz[4*q+3]=v.w;
                v = pn[q]; win[4*q]=v.x; win[4*q+1]=v.y; win[4*q+2]=v.z; win[4*q+3]=v.w;
            }
        }
        const float bR  = b_ih2[u]      + b_hh2[u];
        const float bZ  = b_ih2[32 + u] + b_hh2[32 + u];
        const float bNx = b_ih2[64 + u];
        const float bNh = b_hh2[64 + u];

        float h2 = 0.0f;   // tracked redundantly in both halves
        for (int t = 0; t <= TSTEPS; ++t) {
            float aR = 0.0f, aZ = 0.0f, aN = 0.0f;
            if (t >= 1) {
                const float4* p1 = (const float4*)(&s_h1[(t - 1) & 1][half * 32]); // h1(t-1)
                #pragma unroll
                for (int q = 0; q < 8; ++q) {
                    float4 hv = p1[q];
                    ACC4(aR, wir, q, hv)
                    ACC4(aZ, wiz, q, hv)
                    ACC4(aN, win, q, hv)
                }
                aR += __shfl_xor(aR, 32);
                aZ += __shfl_xor(aZ, 32);
                aN += __shfl_xor(aN, 32);
            }
            __syncthreads();   // B1: gh2 ready
            if (t >= 1) {
                float gr = s_gh2[u];
                float gz = s_gh2[32 + u];
                float gn = s_gh2[64 + u];
                float r2 = fast_sigmoid(aR + gr + bR);
                float z2 = fast_sigmoid(aZ + gz + bZ);
                float n2 = fast_tanh(aN + bNx + r2 * (gn + bNh));
                h2 = n2 + z2 * (h2 - n2);
                if (lane < 32) s_h2[u] = h2;   // h2(t-1); wave1 reads it next tick pre-B1
            }
            __syncthreads();   // B2
        }
        if (lane < 32) out[(size_t)b * 32 + u] = h2;
    }
}

extern "C" void kernel_launch(void* const* d_in, const int* in_sizes, int n_in,
                              void* d_out, int out_size, void* d_ws, size_t ws_size,
                              hipStream_t stream) {
    const float* x     = (const float*)d_in[0];
    const float* W_ih1 = (const float*)d_in[1];
    const float* W_hh1 = (const float*)d_in[2];
    const float* b_ih1 = (const float*)d_in[3];
    const float* b_hh1 = (const float*)d_in[4];
    const float* W_ih2 = (const float*)d_in[5];
    const float* W_hh2 = (const float*)d_in[6];
    const float* b_ih2 = (const float*)d_in[7];
    const float* b_hh2 = (const float*)d_in[8];
    float* out = (float*)d_out;

    gru2_encoder<<<dim3(1024), dim3(192), 0, stream>>>(
        x, W_ih1, W_hh1, b_ih1, b_hh1, W_ih2, W_hh2, b_ih2, b_hh2, out);
}

// Round 5
// 663.205 us; speedup vs baseline: 2.1478x; 2.1478x over previous
//
#include <hip/hip_runtime.h>

#define TSTEPS 1024

typedef _Float16 half2v __attribute__((ext_vector_type(2)));

// v_dot2_f32_f16: acc += a[0]*b[0] + a[1]*b[1], fp32 accumulate, full rate.
__device__ __forceinline__ float hdot2(half2v a, half2v b, float c) {
#if __has_builtin(__builtin_amdgcn_fdot2)
    return __builtin_amdgcn_fdot2(a, b, c, false);
#else
    return fmaf((float)a[0], (float)b[0], fmaf((float)a[1], (float)b[1], c));
#endif
}

__device__ __forceinline__ half2v pack2(float a, float b) {
    half2v r; r[0] = (_Float16)a; r[1] = (_Float16)b; return r;
}
// reinterpret one float (2 packed halfs from an LDS float4 read) as half2
__device__ __forceinline__ half2v f2h2(float f) {
    union { float f; half2v h; } u; u.f = f; return u.h;
}

__device__ __forceinline__ float fast_rcp(float x) { return __builtin_amdgcn_rcpf(x); }
__device__ __forceinline__ float fast_sigmoid(float x) { return fast_rcp(1.0f + __expf(-x)); }
__device__ __forceinline__ float fast_tanh(float x) {
    float e = __expf(2.0f * x);
    return 1.0f - 2.0f * fast_rcp(e + 1.0f);
}

// 16 f16 MACs: 4 packed weights vs 4 half2 lanes of one float4 LDS read
#define DOT4x2(acc_, wt_, b_, p0_, p1_, p2_, p3_)  \
    acc_ = hdot2((wt_)[(b_)+0], p0_, acc_);        \
    acc_ = hdot2((wt_)[(b_)+1], p1_, acc_);        \
    acc_ = hdot2((wt_)[(b_)+2], p2_, acc_);        \
    acc_ = hdot2((wt_)[(b_)+3], p3_, acc_);

// Two waves per block (one block per batch element), layer-pipelined (R3
// structure), but recurrent weights + h-state in packed f16 with fp32
// accumulate via v_dot2_f32_f16:
//   - halves weight VGPR demand (wave0: 96 regs, wave1: 72) so everything
//     fits in the ARCH half of the 256-reg budget -> no AGPR copy traffic
//     (R2-R4's dominant VALU bloat),
//   - halves FMA issue cycles (2 MACs/inst).
// x-path, biases, gate math, h updates all remain fp32.
__global__ __launch_bounds__(128, 2)
void gru2_encoder(const float* __restrict__ x,
                  const float* __restrict__ W_ih1,
                  const float* __restrict__ W_hh1,
                  const float* __restrict__ b_ih1,
                  const float* __restrict__ b_hh1,
                  const float* __restrict__ W_ih2,
                  const float* __restrict__ W_hh2,
                  const float* __restrict__ b_ih2,
                  const float* __restrict__ b_hh2,
                  float* __restrict__ out)
{
    const int b    = blockIdx.x;
    const int lane = threadIdx.x & 63;
    const int wid  = threadIdx.x >> 6;

    __shared__ __align__(16) _Float16 s_h1[2][64];  // h1 double buffer (f16)
    __shared__ __align__(16) _Float16 s_h2[32];     // h2 broadcast (f16)

    const float* xrow = x + (size_t)b * TSTEPS;

    if (wid == 0) {
        // ================= WAVE 0 : GRU1 =================
        const int j = lane;
        half2v wr[32], wz[32], wn[32];   // W_hh1 rows j / 64+j / 128+j, f16-packed
        {
            const float4* pr = (const float4*)(W_hh1 + (size_t)(j) * 64);
            const float4* pz = (const float4*)(W_hh1 + (size_t)(64 + j) * 64);
            const float4* pn = (const float4*)(W_hh1 + (size_t)(128 + j) * 64);
            #pragma unroll
            for (int q = 0; q < 16; ++q) {
                float4 v;
                v = pr[q]; wr[2*q] = pack2(v.x, v.y); wr[2*q+1] = pack2(v.z, v.w);
                v = pz[q]; wz[2*q] = pack2(v.x, v.y); wz[2*q+1] = pack2(v.z, v.w);
                v = pn[q]; wn[2*q] = pack2(v.x, v.y); wn[2*q+1] = pack2(v.z, v.w);
            }
        }
        const float wx_r = W_ih1[j];
        const float wx_z = W_ih1[64 + j];
        const float wx_n = W_ih1[128 + j];
        const float bias_r  = b_ih1[j]      + b_hh1[j];
        const float bias_z  = b_ih1[64 + j] + b_hh1[64 + j];
        const float bias_xn = b_ih1[128 + j];
        const float bias_hn = b_hh1[128 + j];

        float h1 = 0.0f;
        s_h1[0][j] = (_Float16)0.0f;
        s_h1[1][j] = (_Float16)0.0f;
        __syncthreads();   // pairs with wave1 init barrier

        float xs = 0.0f;   // 64 timesteps of x, lane-distributed
        for (int t = 0; t <= TSTEPS; ++t) {
            if (t < TSTEPS) {
                if ((t & 63) == 0) xs = xrow[t + j];   // one coalesced load / 64 ticks
                const float xv = __shfl(xs, t & 63);

                const float4* ph = (const float4*)&s_h1[(t + 1) & 1][0];  // h1(t-1), 8xfloat4
                float acc_r  = fmaf(wx_r, xv, bias_r);
                float acc_z  = fmaf(wx_z, xv, bias_z);
                float acc_hn = bias_hn;
                #pragma unroll
                for (int q = 0; q < 8; ++q) {
                    float4 hv = ph[q];
                    half2v p0 = f2h2(hv.x), p1 = f2h2(hv.y), p2 = f2h2(hv.z), p3 = f2h2(hv.w);
                    DOT4x2(acc_r,  wr, 4*q, p0, p1, p2, p3)
                    DOT4x2(acc_z,  wz, 4*q, p0, p1, p2, p3)
                    DOT4x2(acc_hn, wn, 4*q, p0, p1, p2, p3)
                }
                float r = fast_sigmoid(acc_r);
                float z = fast_sigmoid(acc_z);
                float n = fast_tanh(fmaf(wx_n, xv, bias_xn) + r * acc_hn);
                h1 = n + z * (h1 - n);
                s_h1[t & 1][j] = (_Float16)h1;
            }
            __syncthreads();
        }
    } else {
        // ================= WAVE 1 : GRU2, one step behind =================
        const int u    = lane & 31;   // hidden unit
        const int half = lane >> 5;   // K-split half
        half2v wir[16], wiz[16], win[16];  // W_ih2 rows u/32+u/64+u, cols [half*32,+32)
        half2v whr[8],  whz[8],  whn[8];   // W_hh2 rows u/32+u/64+u, cols [half*16,+16)
        {
            const float4* pr = (const float4*)(W_ih2 + (size_t)(u)      * 64 + half * 32);
            const float4* pz = (const float4*)(W_ih2 + (size_t)(32 + u) * 64 + half * 32);
            const float4* pn = (const float4*)(W_ih2 + (size_t)(64 + u) * 64 + half * 32);
            #pragma unroll
            for (int q = 0; q < 8; ++q) {
                float4 v;
                v = pr[q]; wir[2*q] = pack2(v.x, v.y); wir[2*q+1] = pack2(v.z, v.w);
                v = pz[q]; wiz[2*q] = pack2(v.x, v.y); wiz[2*q+1] = pack2(v.z, v.w);
                v = pn[q]; win[2*q] = pack2(v.x, v.y); win[2*q+1] = pack2(v.z, v.w);
            }
            const float4* qr = (const float4*)(W_hh2 + (size_t)(u)      * 32 + half * 16);
            const float4* qz = (const float4*)(W_hh2 + (size_t)(32 + u) * 32 + half * 16);
            const float4* qn = (const float4*)(W_hh2 + (size_t)(64 + u) * 32 + half * 16);
            #pragma unroll
            for (int q = 0; q < 4; ++q) {
                float4 v;
                v = qr[q]; whr[2*q] = pack2(v.x, v.y); whr[2*q+1] = pack2(v.z, v.w);
                v = qz[q]; whz[2*q] = pack2(v.x, v.y); whz[2*q+1] = pack2(v.z, v.w);
                v = qn[q]; whn[2*q] = pack2(v.x, v.y); whn[2*q+1] = pack2(v.z, v.w);
            }
        }
        const float bR  = b_ih2[u]      + b_hh2[u];
        const float bZ  = b_ih2[32 + u] + b_hh2[32 + u];
        const float bNx = b_ih2[64 + u];
        const float bNh = b_hh2[64 + u];

        float h2 = 0.0f;              // h2[u], replicated in both halves
        if (lane < 32) s_h2[lane] = (_Float16)0.0f;
        __syncthreads();   // pairs with wave0 init barrier

        for (int t = 0; t <= TSTEPS; ++t) {
            if (t >= 1) {
                // x-part: W_ih2 @ h1(t-1), K-half slice: 32 halfs = 4 float4
                const float4* p1 = (const float4*)&s_h1[(t - 1) & 1][half * 32];
                float accR = 0.0f, accZ = 0.0f, accNx = 0.0f, accNh = 0.0f;
                #pragma unroll
                for (int q = 0; q < 4; ++q) {
                    float4 hv = p1[q];
                    half2v p0 = f2h2(hv.x), pq1 = f2h2(hv.y), pq2 = f2h2(hv.z), pq3 = f2h2(hv.w);
                    DOT4x2(accR,  wir, 4*q, p0, pq1, pq2, pq3)
                    DOT4x2(accZ,  wiz, 4*q, p0, pq1, pq2, pq3)
                    DOT4x2(accNx, win, 4*q, p0, pq1, pq2, pq3)
                }
                // h-part: W_hh2 @ h2(t-2), K-half slice: 16 halfs = 2 float4
                const float4* p2 = (const float4*)&s_h2[half * 16];
                #pragma unroll
                for (int q = 0; q < 2; ++q) {
                    float4 hv = p2[q];
                    half2v p0 = f2h2(hv.x), pq1 = f2h2(hv.y), pq2 = f2h2(hv.z), pq3 = f2h2(hv.w);
                    DOT4x2(accR,  whr, 4*q, p0, pq1, pq2, pq3)
                    DOT4x2(accZ,  whz, 4*q, p0, pq1, pq2, pq3)
                    DOT4x2(accNh, whn, 4*q, p0, pq1, pq2, pq3)
                }
                // cross-half reduction (full sums land on both halves)
                accR  += __shfl_xor(accR,  32);
                accZ  += __shfl_xor(accZ,  32);
                accNx += __shfl_xor(accNx, 32);
                accNh += __shfl_xor(accNh, 32);

                float r2 = fast_sigmoid(accR + bR);
                float z2 = fast_sigmoid(accZ + bZ);
                float n2 = fast_tanh(accNx + bNx + r2 * (accNh + bNh));
                h2 = n2 + z2 * (h2 - n2);

                // drain this tick's s_h2 reads before overwriting (same-wave WAR);
                // cross-tick visibility is ordered by the barrier below.
                asm volatile("s_waitcnt lgkmcnt(0)" ::: "memory");
                if (lane < 32) s_h2[u] = (_Float16)h2;
            }
            __syncthreads();
        }

        if (lane < 32) out[(size_t)b * 32 + u] = h2;
    }
}

extern "C" void kernel_launch(void* const* d_in, const int* in_sizes, int n_in,
                              void* d_out, int out_size, void* d_ws, size_t ws_size,
                              hipStream_t stream) {
    const float* x     = (const float*)d_in[0];
    const float* W_ih1 = (const float*)d_in[1];
    const float* W_hh1 = (const float*)d_in[2];
    const float* b_ih1 = (const float*)d_in[3];
    const float* b_hh1 = (const float*)d_in[4];
    const float* W_ih2 = (const float*)d_in[5];
    const float* W_hh2 = (const float*)d_in[6];
    const float* b_ih2 = (const float*)d_in[7];
    const float* b_hh2 = (const float*)d_in[8];
    float* out = (float*)d_out;

    gru2_encoder<<<dim3(1024), dim3(128), 0, stream>>>(
        x, W_ih1, W_hh1, b_ih1, b_hh1, W_ih2, W_hh2, b_ih2, b_hh2, out);
}

// Round 6
// 661.516 us; speedup vs baseline: 2.1533x; 1.0026x over previous
//
#include <hip/hip_runtime.h>

#define TSTEPS 1024

typedef _Float16 half2v __attribute__((ext_vector_type(2)));

// v_dot2_f32_f16: acc += a[0]*b[0] + a[1]*b[1], fp32 accumulate, full rate.
__device__ __forceinline__ float hdot2(half2v a, half2v b, float c) {
#if __has_builtin(__builtin_amdgcn_fdot2)
    return __builtin_amdgcn_fdot2(a, b, c, false);
#else
    return fmaf((float)a[0], (float)b[0], fmaf((float)a[1], (float)b[1], c));
#endif
}

__device__ __forceinline__ half2v pack2(float a, float b) {
    half2v r; r[0] = (_Float16)a; r[1] = (_Float16)b; return r;
}
// reinterpret one float (2 packed halfs from an LDS float4 read) as half2
__device__ __forceinline__ half2v f2h2(float f) {
    union { float f; half2v h; } u; u.f = f; return u.h;
}

__device__ __forceinline__ float fast_rcp(float x) { return __builtin_amdgcn_rcpf(x); }
__device__ __forceinline__ float fast_sigmoid(float x) { return fast_rcp(1.0f + __expf(-x)); }
__device__ __forceinline__ float fast_tanh(float x) {
    float e = __expf(2.0f * x);
    return 1.0f - 2.0f * fast_rcp(e + 1.0f);
}

// 16 f16 MACs: 4 packed weights vs 4 half2 lanes of one float4 LDS read
#define DOT4x2(acc_, wt_, b_, p0_, p1_, p2_, p3_)  \
    acc_ = hdot2((wt_)[(b_)+0], p0_, acc_);        \
    acc_ = hdot2((wt_)[(b_)+1], p1_, acc_);        \
    acc_ = hdot2((wt_)[(b_)+2], p2_, acc_);        \
    acc_ = hdot2((wt_)[(b_)+3], p3_, acc_);

// R5 structure (2 waves/block, layer-pipelined, f16 dot2 path) with ONE
// change: __launch_bounds__(128, 1). At min-waves/EU=2 the register
// allocator split the weight arrays ~100 arch / ~156 AGPR and paid a
// v_accvgpr_read per weight use (~2x VALU bloat, R2-R5 evidence). With a
// 512-reg budget the ~170-reg demand fits entirely in arch VGPRs; HW
// occupancy still lands at 2-3 waves/SIMD since the allocation stays
// well under 256.
__global__ __launch_bounds__(128, 1)
void gru2_encoder(const float* __restrict__ x,
                  const float* __restrict__ W_ih1,
                  const float* __restrict__ W_hh1,
                  const float* __restrict__ b_ih1,
                  const float* __restrict__ b_hh1,
                  const float* __restrict__ W_ih2,
                  const float* __restrict__ W_hh2,
                  const float* __restrict__ b_ih2,
                  const float* __restrict__ b_hh2,
                  float* __restrict__ out)
{
    const int b    = blockIdx.x;
    const int lane = threadIdx.x & 63;
    const int wid  = threadIdx.x >> 6;

    __shared__ __align__(16) _Float16 s_h1[2][64];  // h1 double buffer (f16)
    __shared__ __align__(16) _Float16 s_h2[32];     // h2 broadcast (f16)

    const float* xrow = x + (size_t)b * TSTEPS;

    if (wid == 0) {
        // ================= WAVE 0 : GRU1 =================
        const int j = lane;
        half2v wr[32], wz[32], wn[32];   // W_hh1 rows j / 64+j / 128+j, f16-packed
        {
            const float4* pr = (const float4*)(W_hh1 + (size_t)(j) * 64);
            const float4* pz = (const float4*)(W_hh1 + (size_t)(64 + j) * 64);
            const float4* pn = (const float4*)(W_hh1 + (size_t)(128 + j) * 64);
            #pragma unroll
            for (int q = 0; q < 16; ++q) {
                float4 v;
                v = pr[q]; wr[2*q] = pack2(v.x, v.y); wr[2*q+1] = pack2(v.z, v.w);
                v = pz[q]; wz[2*q] = pack2(v.x, v.y); wz[2*q+1] = pack2(v.z, v.w);
                v = pn[q]; wn[2*q] = pack2(v.x, v.y); wn[2*q+1] = pack2(v.z, v.w);
            }
        }
        const float wx_r = W_ih1[j];
        const float wx_z = W_ih1[64 + j];
        const float wx_n = W_ih1[128 + j];
        const float bias_r  = b_ih1[j]      + b_hh1[j];
        const float bias_z  = b_ih1[64 + j] + b_hh1[64 + j];
        const float bias_xn = b_ih1[128 + j];
        const float bias_hn = b_hh1[128 + j];

        float h1 = 0.0f;
        s_h1[0][j] = (_Float16)0.0f;
        s_h1[1][j] = (_Float16)0.0f;
        __syncthreads();   // pairs with wave1 init barrier

        float xs = 0.0f;   // 64 timesteps of x, lane-distributed
        for (int t = 0; t <= TSTEPS; ++t) {
            if (t < TSTEPS) {
                if ((t & 63) == 0) xs = xrow[t + j];   // one coalesced load / 64 ticks
                const float xv = __shfl(xs, t & 63);

                const float4* ph = (const float4*)&s_h1[(t + 1) & 1][0];  // h1(t-1), 8xfloat4
                float acc_r  = fmaf(wx_r, xv, bias_r);
                float acc_z  = fmaf(wx_z, xv, bias_z);
                float acc_hn = bias_hn;
                #pragma unroll
                for (int q = 0; q < 8; ++q) {
                    float4 hv = ph[q];
                    half2v p0 = f2h2(hv.x), p1 = f2h2(hv.y), p2 = f2h2(hv.z), p3 = f2h2(hv.w);
                    DOT4x2(acc_r,  wr, 4*q, p0, p1, p2, p3)
                    DOT4x2(acc_z,  wz, 4*q, p0, p1, p2, p3)
                    DOT4x2(acc_hn, wn, 4*q, p0, p1, p2, p3)
                }
                float r = fast_sigmoid(acc_r);
                float z = fast_sigmoid(acc_z);
                float n = fast_tanh(fmaf(wx_n, xv, bias_xn) + r * acc_hn);
                h1 = n + z * (h1 - n);
                s_h1[t & 1][j] = (_Float16)h1;
            }
            __syncthreads();
        }
    } else {
        // ================= WAVE 1 : GRU2, one step behind =================
        const int u    = lane & 31;   // hidden unit
        const int half = lane >> 5;   // K-split half
        half2v wir[16], wiz[16], win[16];  // W_ih2 rows u/32+u/64+u, cols [half*32,+32)
        half2v whr[8],  whz[8],  whn[8];   // W_hh2 rows u/32+u/64+u, cols [half*16,+16)
        {
            const float4* pr = (const float4*)(W_ih2 + (size_t)(u)      * 64 + half * 32);
            const float4* pz = (const float4*)(W_ih2 + (size_t)(32 + u) * 64 + half * 32);
            const float4* pn = (const float4*)(W_ih2 + (size_t)(64 + u) * 64 + half * 32);
            #pragma unroll
            for (int q = 0; q < 8; ++q) {
                float4 v;
                v = pr[q]; wir[2*q] = pack2(v.x, v.y); wir[2*q+1] = pack2(v.z, v.w);
                v = pz[q]; wiz[2*q] = pack2(v.x, v.y); wiz[2*q+1] = pack2(v.z, v.w);
                v = pn[q]; win[2*q] = pack2(v.x, v.y); win[2*q+1] = pack2(v.z, v.w);
            }
            const float4* qr = (const float4*)(W_hh2 + (size_t)(u)      * 32 + half * 16);
            const float4* qz = (const float4*)(W_hh2 + (size_t)(32 + u) * 32 + half * 16);
            const float4* qn = (const float4*)(W_hh2 + (size_t)(64 + u) * 32 + half * 16);
            #pragma unroll
            for (int q = 0; q < 4; ++q) {
                float4 v;
                v = qr[q]; whr[2*q] = pack2(v.x, v.y); whr[2*q+1] = pack2(v.z, v.w);
                v = qz[q]; whz[2*q] = pack2(v.x, v.y); whz[2*q+1] = pack2(v.z, v.w);
                v = qn[q]; whn[2*q] = pack2(v.x, v.y); whn[2*q+1] = pack2(v.z, v.w);
            }
        }
        const float bR  = b_ih2[u]      + b_hh2[u];
        const float bZ  = b_ih2[32 + u] + b_hh2[32 + u];
        const float bNx = b_ih2[64 + u];
        const float bNh = b_hh2[64 + u];

        float h2 = 0.0f;              // h2[u], replicated in both halves
        if (lane < 32) s_h2[lane] = (_Float16)0.0f;
        __syncthreads();   // pairs with wave0 init barrier

        for (int t = 0; t <= TSTEPS; ++t) {
            if (t >= 1) {
                // x-part: W_ih2 @ h1(t-1), K-half slice: 32 halfs = 4 float4
                const float4* p1 = (const float4*)&s_h1[(t - 1) & 1][half * 32];
                float accR = 0.0f, accZ = 0.0f, accNx = 0.0f, accNh = 0.0f;
                #pragma unroll
                for (int q = 0; q < 4; ++q) {
                    float4 hv = p1[q];
                    half2v p0 = f2h2(hv.x), pq1 = f2h2(hv.y), pq2 = f2h2(hv.z), pq3 = f2h2(hv.w);
                    DOT4x2(accR,  wir, 4*q, p0, pq1, pq2, pq3)
                    DOT4x2(accZ,  wiz, 4*q, p0, pq1, pq2, pq3)
                    DOT4x2(accNx, win, 4*q, p0, pq1, pq2, pq3)
                }
                // h-part: W_hh2 @ h2(t-2), K-half slice: 16 halfs = 2 float4
                const float4* p2 = (const float4*)&s_h2[half * 16];
                #pragma unroll
                for (int q = 0; q < 2; ++q) {
                    float4 hv = p2[q];
                    half2v p0 = f2h2(hv.x), pq1 = f2h2(hv.y), pq2 = f2h2(hv.z), pq3 = f2h2(hv.w);
                    DOT4x2(accR,  whr, 4*q, p0, pq1, pq2, pq3)
                    DOT4x2(accZ,  whz, 4*q, p0, pq1, pq2, pq3)
                    DOT4x2(accNh, whn, 4*q, p0, pq1, pq2, pq3)
                }
                // cross-half reduction (full sums land on both halves)
                accR  += __shfl_xor(accR,  32);
                accZ  += __shfl_xor(accZ,  32);
                accNx += __shfl_xor(accNx, 32);
                accNh += __shfl_xor(accNh, 32);

                float r2 = fast_sigmoid(accR + bR);
                float z2 = fast_sigmoid(accZ + bZ);
                float n2 = fast_tanh(accNx + bNx + r2 * (accNh + bNh));
                h2 = n2 + z2 * (h2 - n2);

                // drain this tick's s_h2 reads before overwriting (same-wave WAR);
                // cross-tick visibility is ordered by the barrier below.
                asm volatile("s_waitcnt lgkmcnt(0)" ::: "memory");
                if (lane < 32) s_h2[u] = (_Float16)h2;
            }
            __syncthreads();
        }

        if (lane < 32) out[(size_t)b * 32 + u] = h2;
    }
}

extern "C" void kernel_launch(void* const* d_in, const int* in_sizes, int n_in,
                              void* d_out, int out_size, void* d_ws, size_t ws_size,
                              hipStream_t stream) {
    const float* x     = (const float*)d_in[0];
    const float* W_ih1 = (const float*)d_in[1];
    const float* W_hh1 = (const float*)d_in[2];
    const float* b_ih1 = (const float*)d_in[3];
    const float* b_hh1 = (const float*)d_in[4];
    const float* W_ih2 = (const float*)d_in[5];
    const float* W_hh2 = (const float*)d_in[6];
    const float* b_ih2 = (const float*)d_in[7];
    const float* b_hh2 = (const float*)d_in[8];
    float* out = (float*)d_out;

    gru2_encoder<<<dim3(1024), dim3(128), 0, stream>>>(
        x, W_ih1, W_hh1, b_ih1, b_hh1, W_ih2, W_hh2, b_ih2, b_hh2, out);
}

// Round 7
// 606.074 us; speedup vs baseline: 2.3503x; 1.0915x over previous
//
#include <hip/hip_runtime.h>

#define TSTEPS 1024

typedef _Float16 half8 __attribute__((ext_vector_type(8)));
typedef _Float16 half4 __attribute__((ext_vector_type(4)));
typedef float    f32x4 __attribute__((ext_vector_type(4)));

#define MFMA16(A_, B_, C_) __builtin_amdgcn_mfma_f32_16x16x32_f16((A_), (B_), (C_), 0, 0, 0)

__device__ __forceinline__ float fast_rcp(float x) { return __builtin_amdgcn_rcpf(x); }
__device__ __forceinline__ float fast_sigmoid(float x) { return fast_rcp(1.0f + __expf(-x)); }
__device__ __forceinline__ float fast_tanh(float x) {
    float e = __expf(2.0f * x);
    return 1.0f - 2.0f * fast_rcp(e + 1.0f);
}

// load 8 consecutive fp32 and convert to a packed f16 MFMA fragment (4 VGPRs)
__device__ __forceinline__ half8 load_w8(const float* p) {
    const float4 a = ((const float4*)p)[0];
    const float4 b = ((const float4*)p)[1];
    half8 r;
    r[0] = (_Float16)a.x; r[1] = (_Float16)a.y; r[2] = (_Float16)a.z; r[3] = (_Float16)a.w;
    r[4] = (_Float16)b.x; r[5] = (_Float16)b.y; r[6] = (_Float16)b.z; r[7] = (_Float16)b.w;
    return r;
}

// MFMA-batched 2-layer GRU. 64 blocks x 16 chains, 6 waves/block.
//   waves 0..3 : GRU1, unit-group w (units 16w..16w+15). Per tick: 6 MFMAs
//                (r,z,n gate-tiles x 2 K-chunks over h1(t-1)), gate math in
//                C-layout (lane: 4 chains x 1 unit), h1 state fp32 in regs,
//                publish h1(t) as f16 into s_h1[t&1].
//   waves 4..5 : GRU2 unit-group g, ONE STEP BEHIND: consumes h1(t-1) and
//                h2(t-2), 9 MFMAs, writes h2(t-1) into s_h2[(t+1)&1].
// Fragment layouts (m89/m120-verified): A[m=lane&15][k=(lane>>4)*8+j],
// B[k=(lane>>4)*8+j][n=lane&15], C/D: col=lane&15, row=(lane>>4)*4+reg.
// Biases ride in the MFMA C operand. One barrier per tick; h1/h2 double-
// buffered so reads (parity p) and writes (parity 1-p) never collide.
// Weights per wave: 24-36 VGPRs of B-fragments -> no register-allocator
// AGPR offload (the R2-R6 bottleneck).
__global__ __launch_bounds__(384, 1)
void gru2_encoder(const float* __restrict__ x,
                  const float* __restrict__ W_ih1,
                  const float* __restrict__ W_hh1,
                  const float* __restrict__ b_ih1,
                  const float* __restrict__ b_hh1,
                  const float* __restrict__ W_ih2,
                  const float* __restrict__ W_hh2,
                  const float* __restrict__ b_ih2,
                  const float* __restrict__ b_hh2,
                  float* __restrict__ out)
{
    const int blk  = blockIdx.x;    // 64 blocks, 16 chains each
    const int tid  = threadIdx.x;   // 384
    const int lane = tid & 63;
    const int wid  = tid >> 6;      // 0..5
    const int nl   = lane & 15;     // tile column (unit within group)
    const int quad = lane >> 4;     // 0..3
    const int m0   = quad * 4;      // C-layout row base (chain within block)
    const int chain0 = blk * 16;

    // s_h1 row stride 72 f16 = 144B (9x16B: b128-aligned, 2-way-bank-free)
    __shared__ __align__(16) _Float16 s_h1[2][16][72];
    __shared__ __align__(16) _Float16 s_h2[2][16][40];
    __shared__ __align__(16) _Float16 s_x[TSTEPS][16];   // x staged f16, [t][chain]

    // ---- one-time staging: x (transposed, f16) + zero h buffers
    for (int idx = tid; idx < 16 * TSTEPS; idx += 384) {
        const int m = idx >> 10, t = idx & (TSTEPS - 1);
        s_x[t][m] = (_Float16)x[(size_t)(chain0 + m) * TSTEPS + t];
    }
    {
        _Float16* p1 = &s_h1[0][0][0];
        for (int idx = tid; idx < 2 * 16 * 72; idx += 384) p1[idx] = (_Float16)0.0f;
        _Float16* p2 = &s_h2[0][0][0];
        for (int idx = tid; idx < 2 * 16 * 40; idx += 384) p2[idx] = (_Float16)0.0f;
    }
    __syncthreads();

    if (wid < 4) {
        // ================= GRU1, unit-group w =================
        const int u = wid * 16 + nl;   // unit 0..63
        // B-fragments: gate rows {u, 64+u, 128+u} of W_hh1[192][64], K-chunks 0/1
        const half8 Br0 = load_w8(W_hh1 + (size_t)(u)       * 64 + quad * 8);
        const half8 Br1 = load_w8(W_hh1 + (size_t)(u)       * 64 + 32 + quad * 8);
        const half8 Bz0 = load_w8(W_hh1 + (size_t)(64 + u)  * 64 + quad * 8);
        const half8 Bz1 = load_w8(W_hh1 + (size_t)(64 + u)  * 64 + 32 + quad * 8);
        const half8 Bn0 = load_w8(W_hh1 + (size_t)(128 + u) * 64 + quad * 8);
        const half8 Bn1 = load_w8(W_hh1 + (size_t)(128 + u) * 64 + 32 + quad * 8);
        const float wxr = W_ih1[u], wxz = W_ih1[64 + u], wxn = W_ih1[128 + u];
        const float bRs = b_ih1[u] + b_hh1[u];
        const float bZs = b_ih1[64 + u] + b_hh1[64 + u];
        const float bNx = b_ih1[128 + u];
        const float bNh = b_hh1[128 + u];
        const f32x4 cR = {bRs, bRs, bRs, bRs};
        const f32x4 cZ = {bZs, bZs, bZs, bZs};
        const f32x4 cN = {bNh, bNh, bNh, bNh};

        float h1s[4] = {0.0f, 0.0f, 0.0f, 0.0f};   // h1[chain m0+i][unit u], fp32

        for (int t = 0; t <= TSTEPS; ++t) {
            if (t < TSTEPS) {
                const int pr = (t + 1) & 1;            // parity holding h1(t-1)
                const half8 A0 = *(const half8*)&s_h1[pr][nl][quad * 8];
                const half8 A1 = *(const half8*)&s_h1[pr][nl][32 + quad * 8];
                f32x4 aR = MFMA16(A0, Br0, cR); aR = MFMA16(A1, Br1, aR);
                f32x4 aZ = MFMA16(A0, Bz0, cZ); aZ = MFMA16(A1, Bz1, aZ);
                f32x4 aN = MFMA16(A0, Bn0, cN); aN = MFMA16(A1, Bn1, aN);
                const half4 xh = *(const half4*)&s_x[t][m0];
                #pragma unroll
                for (int i = 0; i < 4; ++i) {
                    const float xv = (float)xh[i];
                    const float r = fast_sigmoid(fmaf(wxr, xv, aR[i]));
                    const float z = fast_sigmoid(fmaf(wxz, xv, aZ[i]));
                    const float n = fast_tanh(fmaf(wxn, xv, bNx) + r * aN[i]);
                    h1s[i] = n + z * (h1s[i] - n);
                    s_h1[t & 1][m0 + i][u] = (_Float16)h1s[i];
                }
            }
            __syncthreads();
        }
    } else {
        // ================= GRU2, unit-group g, one step behind =================
        const int u = (wid - 4) * 16 + nl;   // unit 0..31
        // W_ih2[96][64]: gate rows {u, 32+u, 64+u}, K-chunks 0/1
        const half8 BiR0 = load_w8(W_ih2 + (size_t)(u)      * 64 + quad * 8);
        const half8 BiR1 = load_w8(W_ih2 + (size_t)(u)      * 64 + 32 + quad * 8);
        const half8 BiZ0 = load_w8(W_ih2 + (size_t)(32 + u) * 64 + quad * 8);
        const half8 BiZ1 = load_w8(W_ih2 + (size_t)(32 + u) * 64 + 32 + quad * 8);
        const half8 BiN0 = load_w8(W_ih2 + (size_t)(64 + u) * 64 + quad * 8);
        const half8 BiN1 = load_w8(W_ih2 + (size_t)(64 + u) * 64 + 32 + quad * 8);
        // W_hh2[96][32]: K=32 spans one chunk exactly
        const half8 BhR = load_w8(W_hh2 + (size_t)(u)      * 32 + quad * 8);
        const half8 BhZ = load_w8(W_hh2 + (size_t)(32 + u) * 32 + quad * 8);
        const half8 BhN = load_w8(W_hh2 + (size_t)(64 + u) * 32 + quad * 8);
        const float bR2  = b_ih2[u] + b_hh2[u];
        const float bZ2  = b_ih2[32 + u] + b_hh2[32 + u];
        const float bNx2 = b_ih2[64 + u];
        const float bNh2 = b_hh2[64 + u];
        const f32x4 cR2  = {bR2, bR2, bR2, bR2};
        const f32x4 cZ2  = {bZ2, bZ2, bZ2, bZ2};
        const f32x4 cNx2 = {bNx2, bNx2, bNx2, bNx2};
        const f32x4 cNh2 = {bNh2, bNh2, bNh2, bNh2};

        float h2s[4] = {0.0f, 0.0f, 0.0f, 0.0f};   // h2[chain m0+i][unit u], fp32

        for (int t = 0; t <= TSTEPS; ++t) {
            if (t >= 1) {
                const int pA = (t + 1) & 1;            // parity of h1(t-1)
                const half8 A0 = *(const half8*)&s_h1[pA][nl][quad * 8];
                const half8 A1 = *(const half8*)&s_h1[pA][nl][32 + quad * 8];
                const half8 Ah = *(const half8*)&s_h2[t & 1][nl][quad * 8];  // h2(t-2)
                f32x4 aR = MFMA16(A0, BiR0, cR2); aR = MFMA16(A1, BiR1, aR);
                aR = MFMA16(Ah, BhR, aR);
                f32x4 aZ = MFMA16(A0, BiZ0, cZ2); aZ = MFMA16(A1, BiZ1, aZ);
                aZ = MFMA16(Ah, BhZ, aZ);
                f32x4 aNx = MFMA16(A0, BiN0, cNx2); aNx = MFMA16(A1, BiN1, aNx);
                f32x4 aNh = MFMA16(Ah, BhN, cNh2);
                #pragma unroll
                for (int i = 0; i < 4; ++i) {
                    const float r2 = fast_sigmoid(aR[i]);
                    const float z2 = fast_sigmoid(aZ[i]);
                    const float n2 = fast_tanh(aNx[i] + r2 * aNh[i]);
                    h2s[i] = n2 + z2 * (h2s[i] - n2);
                    s_h2[(t + 1) & 1][m0 + i][u] = (_Float16)h2s[i];  // h2(t-1)
                }
            }
            __syncthreads();
        }

        #pragma unroll
        for (int i = 0; i < 4; ++i)
            out[(size_t)(chain0 + m0 + i) * 32 + u] = h2s[i];
    }
}

extern "C" void kernel_launch(void* const* d_in, const int* in_sizes, int n_in,
                              void* d_out, int out_size, void* d_ws, size_t ws_size,
                              hipStream_t stream) {
    const float* x     = (const float*)d_in[0];
    const float* W_ih1 = (const float*)d_in[1];
    const float* W_hh1 = (const float*)d_in[2];
    const float* b_ih1 = (const float*)d_in[3];
    const float* b_hh1 = (const float*)d_in[4];
    const float* W_ih2 = (const float*)d_in[5];
    const float* W_hh2 = (const float*)d_in[6];
    const float* b_ih2 = (const float*)d_in[7];
    const float* b_hh2 = (const float*)d_in[8];
    float* out = (float*)d_out;

    gru2_encoder<<<dim3(64), dim3(384), 0, stream>>>(
        x, W_ih1, W_hh1, b_ih1, b_hh1, W_ih2, W_hh2, b_ih2, b_hh2, out);
}

// Round 8
// 592.269 us; speedup vs baseline: 2.4051x; 1.0233x over previous
//
#include <hip/hip_runtime.h>

#define TSTEPS 1024

typedef _Float16 half8 __attribute__((ext_vector_type(8)));
typedef _Float16 half4 __attribute__((ext_vector_type(4)));
typedef float    f32x4 __attribute__((ext_vector_type(4)));

#define MFMA16(A_, B_, C_) __builtin_amdgcn_mfma_f32_16x16x32_f16((A_), (B_), (C_), 0, 0, 0)

__device__ __forceinline__ float fast_rcp(float x) { return __builtin_amdgcn_rcpf(x); }
__device__ __forceinline__ float fast_sigmoid(float x) { return fast_rcp(1.0f + __expf(-x)); }
__device__ __forceinline__ float fast_tanh(float x) {
    float e = __expf(2.0f * x);
    return 1.0f - 2.0f * fast_rcp(e + 1.0f);
}

// load 8 consecutive fp32 and convert to a packed f16 MFMA fragment (4 VGPRs)
__device__ __forceinline__ half8 load_w8(const float* p) {
    const float4 a = ((const float4*)p)[0];
    const float4 b = ((const float4*)p)[1];
    half8 r;
    r[0] = (_Float16)a.x; r[1] = (_Float16)a.y; r[2] = (_Float16)a.z; r[3] = (_Float16)a.w;
    r[4] = (_Float16)b.x; r[5] = (_Float16)b.y; r[6] = (_Float16)b.z; r[7] = (_Float16)b.w;
    return r;
}

// MFMA-batched 2-layer GRU, R7 structure with SWAPPED operands:
// A = weights (static regs), B = h-state, D[m=unit][n=chain].
// LDS h layout is [chain][unit], so per lane:
//   B-frag read  = ds_read_b128 (chain nl, units quad*8..+8)      [contiguous]
//   h publish    = ds_write_b64 (chain nl, units U0+quad*4..+4)   [contiguous]
//   out          = global_store_dwordx4                            [contiguous]
// vs R7's 4x ds_write_b16 scatter / 4x scalar stores (the conflict source).
//   waves 0..3 : GRU1 unit-tile wid (units 16w..16w+15), h1 fp32 in regs.
//   waves 4..5 : GRU2 unit-tile, ONE STEP BEHIND (h1(t-1), h2(t-2)).
// Fragment mappings (m89/m120-verified): A[m=lane&15][k=quad*8+j],
// B[k=quad*8+j][n=lane&15], C/D: col(n)=lane&15, row(m)=quad*4+reg.
__global__ __launch_bounds__(384, 1)
void gru2_encoder(const float* __restrict__ x,
                  const float* __restrict__ W_ih1,
                  const float* __restrict__ W_hh1,
                  const float* __restrict__ b_ih1,
                  const float* __restrict__ b_hh1,
                  const float* __restrict__ W_ih2,
                  const float* __restrict__ W_hh2,
                  const float* __restrict__ b_ih2,
                  const float* __restrict__ b_hh2,
                  float* __restrict__ out)
{
    const int blk  = blockIdx.x;    // 64 blocks, 16 chains each
    const int tid  = threadIdx.x;   // 384
    const int lane = tid & 63;
    const int wid  = tid >> 6;      // 0..5
    const int nl   = lane & 15;     // chain (n-col of D; m-row of A)
    const int quad = lane >> 4;     // 0..3
    const int chain0 = blk * 16;

    __shared__ __align__(16) _Float16 s_h1[2][16][72];   // [parity][chain][unit(64)+pad]
    __shared__ __align__(16) _Float16 s_h2[2][16][40];   // [parity][chain][unit(32)+pad]
    __shared__ __align__(16) _Float16 s_x[TSTEPS][16];   // x staged f16, [t][chain]

    // ---- one-time staging: x (transposed, f16) + zero h buffers
    for (int idx = tid; idx < 16 * TSTEPS; idx += 384) {
        const int m = idx >> 10, t = idx & (TSTEPS - 1);
        s_x[t][m] = (_Float16)x[(size_t)(chain0 + m) * TSTEPS + t];
    }
    {
        _Float16* p1 = &s_h1[0][0][0];
        for (int idx = tid; idx < 2 * 16 * 72; idx += 384) p1[idx] = (_Float16)0.0f;
        _Float16* p2 = &s_h2[0][0][0];
        for (int idx = tid; idx < 2 * 16 * 40; idx += 384) p2[idx] = (_Float16)0.0f;
    }
    __syncthreads();

    if (wid < 4) {
        // ================= GRU1, unit-tile wid =================
        const int U0 = wid * 16;          // unit base of this tile
        const int ur = U0 + nl;           // A-fragment row unit (m = nl)
        const int u4 = U0 + quad * 4;     // first of this lane's 4 D units
        // A-fragments: W_hh1[192][64], gate rows {ur, 64+ur, 128+ur}, K-chunks 0/1
        const half8 aWr0 = load_w8(W_hh1 + (size_t)(ur)       * 64 + 0  + quad * 8);
        const half8 aWr1 = load_w8(W_hh1 + (size_t)(ur)       * 64 + 32 + quad * 8);
        const half8 aWz0 = load_w8(W_hh1 + (size_t)(64 + ur)  * 64 + 0  + quad * 8);
        const half8 aWz1 = load_w8(W_hh1 + (size_t)(64 + ur)  * 64 + 32 + quad * 8);
        const half8 aWn0 = load_w8(W_hh1 + (size_t)(128 + ur) * 64 + 0  + quad * 8);
        const half8 aWn1 = load_w8(W_hh1 + (size_t)(128 + ur) * 64 + 32 + quad * 8);
        // per-lane 4 D-units: x weights + biases as aligned float4
        const float4 wxr = *(const float4*)(W_ih1 + u4);
        const float4 wxz = *(const float4*)(W_ih1 + 64 + u4);
        const float4 wxn = *(const float4*)(W_ih1 + 128 + u4);
        const float4 bi_r = *(const float4*)(b_ih1 + u4);
        const float4 bh_r = *(const float4*)(b_hh1 + u4);
        const float4 bi_z = *(const float4*)(b_ih1 + 64 + u4);
        const float4 bh_z = *(const float4*)(b_hh1 + 64 + u4);
        const float4 bi_n = *(const float4*)(b_ih1 + 128 + u4);
        const float4 bh_n = *(const float4*)(b_hh1 + 128 + u4);
        const f32x4 cR = {bi_r.x + bh_r.x, bi_r.y + bh_r.y, bi_r.z + bh_r.z, bi_r.w + bh_r.w};
        const f32x4 cZ = {bi_z.x + bh_z.x, bi_z.y + bh_z.y, bi_z.z + bh_z.z, bi_z.w + bh_z.w};
        const f32x4 cN = {bh_n.x, bh_n.y, bh_n.z, bh_n.w};
        const float wxr4[4] = {wxr.x, wxr.y, wxr.z, wxr.w};
        const float wxz4[4] = {wxz.x, wxz.y, wxz.z, wxz.w};
        const float wxn4[4] = {wxn.x, wxn.y, wxn.z, wxn.w};
        const float bNx4[4] = {bi_n.x, bi_n.y, bi_n.z, bi_n.w};

        float h1s[4] = {0.0f, 0.0f, 0.0f, 0.0f};   // h1[u4+i][chain nl]

        for (int t = 0; t <= TSTEPS; ++t) {
            if (t < TSTEPS) {
                const int pr = (t + 1) & 1;            // parity holding h1(t-1)
                const half8 B0 = *(const half8*)&s_h1[pr][nl][quad * 8];        // k 0..31
                const half8 B1 = *(const half8*)&s_h1[pr][nl][32 + quad * 8];   // k 32..63
                f32x4 aR = MFMA16(aWr0, B0, cR); aR = MFMA16(aWr1, B1, aR);
                f32x4 aZ = MFMA16(aWz0, B0, cZ); aZ = MFMA16(aWz1, B1, aZ);
                f32x4 aN = MFMA16(aWn0, B0, cN); aN = MFMA16(aWn1, B1, aN);
                const float xv = (float)s_x[t][nl];
                half4 hv;
                #pragma unroll
                for (int i = 0; i < 4; ++i) {
                    const float r = fast_sigmoid(fmaf(wxr4[i], xv, aR[i]));
                    const float z = fast_sigmoid(fmaf(wxz4[i], xv, aZ[i]));
                    const float n = fast_tanh(fmaf(wxn4[i], xv, bNx4[i]) + r * aN[i]);
                    h1s[i] = n + z * (h1s[i] - n);
                    hv[i] = (_Float16)h1s[i];
                }
                *(half4*)&s_h1[t & 1][nl][u4] = hv;    // one contiguous b64
            }
            __syncthreads();
        }
    } else {
        // ================= GRU2, unit-tile (wid-4), one step behind =================
        const int V0 = (wid - 4) * 16;    // h2-unit base
        const int vr = V0 + nl;           // A-fragment row unit
        const int v4 = V0 + quad * 4;     // lane's 4 D units
        // W_ih2[96][64] rows {vr, 32+vr, 64+vr}, K-chunks 0/1 (over h1)
        const half8 AiR0 = load_w8(W_ih2 + (size_t)(vr)      * 64 + 0  + quad * 8);
        const half8 AiR1 = load_w8(W_ih2 + (size_t)(vr)      * 64 + 32 + quad * 8);
        const half8 AiZ0 = load_w8(W_ih2 + (size_t)(32 + vr) * 64 + 0  + quad * 8);
        const half8 AiZ1 = load_w8(W_ih2 + (size_t)(32 + vr) * 64 + 32 + quad * 8);
        const half8 AiN0 = load_w8(W_ih2 + (size_t)(64 + vr) * 64 + 0  + quad * 8);
        const half8 AiN1 = load_w8(W_ih2 + (size_t)(64 + vr) * 64 + 32 + quad * 8);
        // W_hh2[96][32]: K=32 in one chunk (over h2)
        const half8 AhR = load_w8(W_hh2 + (size_t)(vr)      * 32 + quad * 8);
        const half8 AhZ = load_w8(W_hh2 + (size_t)(32 + vr) * 32 + quad * 8);
        const half8 AhN = load_w8(W_hh2 + (size_t)(64 + vr) * 32 + quad * 8);
        const float4 bi_r = *(const float4*)(b_ih2 + v4);
        const float4 bh_r = *(const float4*)(b_hh2 + v4);
        const float4 bi_z = *(const float4*)(b_ih2 + 32 + v4);
        const float4 bh_z = *(const float4*)(b_hh2 + 32 + v4);
        const float4 bi_n = *(const float4*)(b_ih2 + 64 + v4);
        const float4 bh_n = *(const float4*)(b_hh2 + 64 + v4);
        const f32x4 cR  = {bi_r.x + bh_r.x, bi_r.y + bh_r.y, bi_r.z + bh_r.z, bi_r.w + bh_r.w};
        const f32x4 cZ  = {bi_z.x + bh_z.x, bi_z.y + bh_z.y, bi_z.z + bh_z.z, bi_z.w + bh_z.w};
        const f32x4 cNx = {bi_n.x, bi_n.y, bi_n.z, bi_n.w};
        const f32x4 cNh = {bh_n.x, bh_n.y, bh_n.z, bh_n.w};

        float h2s[4] = {0.0f, 0.0f, 0.0f, 0.0f};   // h2[v4+i][chain nl]

        for (int t = 0; t <= TSTEPS; ++t) {
            if (t >= 1) {
                const int pA = (t + 1) & 1;            // parity of h1(t-1)
                const half8 B0 = *(const half8*)&s_h1[pA][nl][quad * 8];
                const half8 B1 = *(const half8*)&s_h1[pA][nl][32 + quad * 8];
                const half8 Bh = *(const half8*)&s_h2[t & 1][nl][quad * 8];   // h2(t-2)
                f32x4 aR = MFMA16(AiR0, B0, cR);  aR = MFMA16(AiR1, B1, aR);
                aR = MFMA16(AhR, Bh, aR);
                f32x4 aZ = MFMA16(AiZ0, B0, cZ);  aZ = MFMA16(AiZ1, B1, aZ);
                aZ = MFMA16(AhZ, Bh, aZ);
                f32x4 aNx = MFMA16(AiN0, B0, cNx); aNx = MFMA16(AiN1, B1, aNx);
                f32x4 aNh = MFMA16(AhN, Bh, cNh);
                half4 hv;
                #pragma unroll
                for (int i = 0; i < 4; ++i) {
                    const float r2 = fast_sigmoid(aR[i]);
                    const float z2 = fast_sigmoid(aZ[i]);
                    const float n2 = fast_tanh(aNx[i] + r2 * aNh[i]);
                    h2s[i] = n2 + z2 * (h2s[i] - n2);
                    hv[i] = (_Float16)h2s[i];
                }
                *(half4*)&s_h2[(t + 1) & 1][nl][v4] = hv;   // h2(t-1), one b64
            }
            __syncthreads();
        }

        float4 o = {h2s[0], h2s[1], h2s[2], h2s[3]};
        *(float4*)(out + (size_t)(chain0 + nl) * 32 + v4) = o;   // one dwordx4
    }
}

extern "C" void kernel_launch(void* const* d_in, const int* in_sizes, int n_in,
                              void* d_out, int out_size, void* d_ws, size_t ws_size,
                              hipStream_t stream) {
    const float* x     = (const float*)d_in[0];
    const float* W_ih1 = (const float*)d_in[1];
    const float* W_hh1 = (const float*)d_in[2];
    const float* b_ih1 = (const float*)d_in[3];
    const float* b_hh1 = (const float*)d_in[4];
    const float* W_ih2 = (const float*)d_in[5];
    const float* W_hh2 = (const float*)d_in[6];
    const float* b_ih2 = (const float*)d_in[7];
    const float* b_hh2 = (const float*)d_in[8];
    float* out = (float*)d_out;

    gru2_encoder<<<dim3(64), dim3(384), 0, stream>>>(
        x, W_ih1, W_hh1, b_ih1, b_hh1, W_ih2, W_hh2, b_ih2, b_hh2, out);
}